// Round 8
// baseline (5363.564 us; speedup 1.0000x reference)
//
#include <hip/hip_runtime.h>

typedef unsigned short u16;
typedef __bf16 bf16x8 __attribute__((ext_vector_type(8)));
typedef float f32x4 __attribute__((ext_vector_type(4)));
typedef short s8v __attribute__((ext_vector_type(8)));
typedef short s4v __attribute__((ext_vector_type(4)));

#define NND 65536   // nodes
#define CH  16384   // FFN/policy row-chunk (arena 64 MB)

#define VM3 asm volatile("s_waitcnt vmcnt(3)" ::: "memory")
#define VM0 asm volatile("s_waitcnt vmcnt(0)" ::: "memory")
#define BAR __builtin_amdgcn_s_barrier()
#define SCB __builtin_amdgcn_sched_barrier(0)

__device__ __forceinline__ float bs2f(short s) {
    union { unsigned u; float f; } x;
    x.u = ((unsigned)(u16)s) << 16;
    return x.f;
}
__device__ __forceinline__ u16 f2bu(float f) {
    union { float f; unsigned u; } x;
    x.f = f;
    unsigned r = x.u + 0x7FFFu + ((x.u >> 16) & 1u);
    return (u16)(r >> 16);
}
__device__ __forceinline__ void g2l16(const void* g, void* l) {
    __builtin_amdgcn_global_load_lds((const __attribute__((address_space(1))) void*)g,
                                     (__attribute__((address_space(3))) void*)l, 16, 0, 0);
}
// grouped XCD swizzle: all col-blocks (bn) of a row-tile (bm) land on one XCD
__device__ __forceinline__ void xcd_decode(int lognbn, int& bm, int& bn) {
    int flat = blockIdx.x;
    int cpx = gridDim.x >> 3;
    int virt = (flat & 7) * cpx + (flat >> 3);
    bm = virt >> lognbn;
    bn = virt & ((1 << lognbn) - 1);
}

// ---------------------------------------------------------------------------
// Per-layer wq/wk/wv conversion: fp32 (512x64) -> bf16 transposed (64x512).
// ---------------------------------------------------------------------------
__global__ void k_conv_qkv(const float* __restrict__ wq, const float* __restrict__ wk,
                           const float* __restrict__ wv, u16* __restrict__ wqT,
                           u16* __restrict__ wkT, u16* __restrict__ wvT, int l)
{
    int bz = blockIdx.y;
    const float* in; u16* out;
    if (bz < 40) {
        int h = bz / 5, r = bz % 5;
        in  = wk + (size_t)((l * 8 + h) * 5 + r) * 32768;
        out = wkT + (size_t)r * 262144 + h * 64 * 512;
    } else if (bz < 80) {
        int t = bz - 40; int h = t / 5, r = t % 5;
        in  = wv + (size_t)((l * 8 + h) * 5 + r) * 32768;
        out = wvT + (size_t)r * 262144 + h * 64 * 512;
    } else {
        int h = bz - 80;
        in  = wq + (size_t)(l * 8 + h) * 32768;
        out = wqT + h * 64 * 512;
    }
    int d0 = blockIdx.x * 32;
    __shared__ float s[32][65];
    int tid = threadIdx.x;
    int di = tid >> 3, k8 = (tid & 7) * 8;
    const float* ip = in + (long)(d0 + di) * 64 + k8;
    #pragma unroll
    for (int i = 0; i < 8; ++i) s[di][k8 + i] = ip[i];
    __syncthreads();
    int kk = tid >> 2, d8 = (tid & 3) * 8;
    s8v o;
    #pragma unroll
    for (int i = 0; i < 8; ++i) o[i] = (short)f2bu(s[d8 + i][kk]);
    *(s8v*)(out + (long)kk * 512 + d0 + d8) = o;
}

// Generic transpose: in (R x C fp32) -> out (C x R bf16). grid = (R/32)*(C/32).
__global__ void k_convT(const float* __restrict__ in, u16* __restrict__ out, int R, int C)
{
    int tiles_c = C >> 5;
    int tr = blockIdx.x / tiles_c, tc = blockIdx.x % tiles_c;
    int r0 = tr * 32, c0 = tc * 32;
    __shared__ float s[32][33];
    int tid = threadIdx.x;
    int ri = tid >> 3, c4 = (tid & 7) * 4;
    const float4 v = *(const float4*)(in + (long)(r0 + ri) * C + c0 + c4);
    s[ri][c4] = v.x; s[ri][c4 + 1] = v.y; s[ri][c4 + 2] = v.z; s[ri][c4 + 3] = v.w;
    __syncthreads();
    int ci = tid >> 3, r4 = (tid & 7) * 4;
    s4v o;
    #pragma unroll
    for (int i = 0; i < 4; ++i) o[i] = (short)f2bu(s[r4 + i][ci]);
    *(s4v*)(out + (long)(c0 + ci) * R + r0 + r4) = o;
}

// ---------------------------------------------------------------------------
// Embed: xbf = bf16(x6 @ embed_w + embed_b). block=512 (one row per block)
// ---------------------------------------------------------------------------
__global__ void k_embed(const float* __restrict__ x6, const float* __restrict__ ew,
                        const float* __restrict__ eb, u16* __restrict__ xbf)
{
    int n = blockIdx.x, j = threadIdx.x;
    const float* r = x6 + (long)n * 6;
    float a = eb[j] + r[0] * ew[j] + r[1] * ew[512 + j] + r[2] * ew[1024 + j]
            + r[3] * ew[1536 + j] + r[4] * ew[2048 + j] + r[5] * ew[2560 + j];
    xbf[(long)n * 512 + j] = f2bu(a);
}

// ---------------------------------------------------------------------------
// bf16 MFMA GEMM: 256x128 tile, BK=32, 512 thr / 8 waves (4x2, wave tile
// 64x64), bank-conflict swizzle, 3-buffer LDS pipeline, counted vmcnt,
// setprio. BT = Ncols x K row-major. grouped-XCD 1-D grid.
// ---------------------------------------------------------------------------
template<bool BIAS, bool RELU, bool ADDX>
__global__ __launch_bounds__(512, 2)
void k_gemm(const u16* __restrict__ A, const u16* __restrict__ BT,
            u16* __restrict__ C, const float* __restrict__ bias,
            const u16* __restrict__ resid, int K, int Ncols, int lognbn)
{
    __shared__ u16 sA[3][8192];     // 256 rows x 32 K per buffer
    __shared__ u16 sB[3][4096];     // 128 rows x 32 K per buffer
    const int tid = threadIdx.x;
    const int wave = tid >> 6, lane = tid & 63;
    int bm, bn;
    xcd_decode(lognbn, bm, bn);

    const int arow = tid >> 2;                              // 0..127
    const int acol8 = ((tid & 3) ^ ((tid >> 3) & 3)) * 8;   // source pre-swizzle
    const u16* pa0 = A + ((long)bm * 256 + arow) * K + acol8;
    const u16* pa1 = pa0 + (long)128 * K;
    const u16* pb  = BT + ((long)bn * 128 + arow) * K + acol8;

    char* sAc = (char*)sA;
    char* sBc = (char*)sB;
    const int dst = tid * 16;

    f32x4 acc[4][4] = {};

    const int wm = wave >> 1, wn = wave & 1;                // 4x2 wave grid
    const int fr = lane & 15;
    const int g4 = lane >> 4;
    const int kbs = (g4 ^ ((fr >> 1) & 3)) * 16;            // swizzled read slot
    const char* ra = sAc + (wm * 64 + fr) * 64 + kbs;
    const char* rb = sBc + (wn * 64 + fr) * 64 + kbs;

    auto STAGE = [&](int buf) {
        char* a = sAc + buf * 16384;
        g2l16(pa0, a + dst);
        g2l16(pa1, a + 8192 + dst);
        g2l16(pb, sBc + buf * 8192 + dst);
        pa0 += 32; pa1 += 32; pb += 32;
    };

    const int NT = K >> 5;
    STAGE(0); STAGE(1);
    VM3; BAR; SCB;

    int cur = 0, nx2 = 2;
    for (int t = 0; t < NT; ++t) {
        if (t + 2 < NT) STAGE(nx2);
        bf16x8 af[4], bfr[4];
        const char* rac = ra + cur * 16384;
        const char* rbc = rb + cur * 8192;
        #pragma unroll
        for (int mi = 0; mi < 4; ++mi) af[mi] = *(const bf16x8*)(rac + mi * 1024);
        #pragma unroll
        for (int ni = 0; ni < 4; ++ni) bfr[ni] = *(const bf16x8*)(rbc + ni * 1024);
        __builtin_amdgcn_s_setprio(1);
        #pragma unroll
        for (int mi = 0; mi < 4; ++mi)
            #pragma unroll
            for (int ni = 0; ni < 4; ++ni)
                acc[mi][ni] = __builtin_amdgcn_mfma_f32_16x16x32_bf16(af[mi], bfr[ni], acc[mi][ni], 0, 0, 0);
        __builtin_amdgcn_s_setprio(0);
        if (t + 2 < NT)      { VM3; }
        else if (t + 1 < NT) { VM0; }
        BAR; SCB;
        cur = (cur == 2) ? 0 : cur + 1;
        nx2 = (nx2 == 2) ? 0 : nx2 + 1;
    }

    const int crow0 = bm * 256 + wm * 64 + g4 * 4;
    const int ccol0 = bn * 128 + wn * 64 + fr;
    #pragma unroll
    for (int mi = 0; mi < 4; ++mi) {
        #pragma unroll
        for (int ni = 0; ni < 4; ++ni) {
            int col = ccol0 + ni * 16;
            float bv = BIAS ? bias[col] : 0.f;
            #pragma unroll
            for (int j = 0; j < 4; ++j) {
                int row = crow0 + mi * 16 + j;
                float v = acc[mi][ni][j] + bv;
                if (ADDX) v += bs2f(resid[(long)row * Ncols + col]);
                if (RELU) v = fmaxf(v, 0.f);
                C[(long)row * Ncols + col] = f2bu(v);
            }
        }
    }
}

// ---------------------------------------------------------------------------
// Fused attention pass A: phase 0 computes Q tile (registers, packed bf16),
// phases 1..5 compute K_r; S[h*5+r][n] = 0.125*dot64(Q,K) via elementwise
// frag product + 16-lane shfl reduce. 256x128 tile, 8 waves, pipelined.
// ---------------------------------------------------------------------------
__global__ __launch_bounds__(512, 2)
void k_attnKS(const u16* __restrict__ xbf, const u16* __restrict__ wqT,
              const u16* __restrict__ wkT, const int* __restrict__ adj,
              float* __restrict__ S)
{
    __shared__ u16 sA[3][8192];
    __shared__ u16 sB[3][4096];
    const int tid = threadIdx.x;
    const int wave = tid >> 6, lane = tid & 63;
    int bm, bn;
    xcd_decode(2, bm, bn);
    const int arow = tid >> 2;
    const int acol8 = ((tid & 3) ^ ((tid >> 3) & 3)) * 8;

    char* sAc = (char*)sA;
    char* sBc = (char*)sB;
    const int dst = tid * 16;

    const int wm = wave >> 1, wn = wave & 1;
    const int fr = lane & 15;
    const int g4 = lane >> 4;
    const int kbs = (g4 ^ ((fr >> 1) & 3)) * 16;
    const char* ra = sAc + (wm * 64 + fr) * 64 + kbs;
    const char* rb = sBc + (wn * 64 + fr) * 64 + kbs;

    const int h = bn * 2 + wn;
    const int rowbase = bm * 256 + wm * 64;

    unsigned qp[4][4][2];   // Q fragments, packed bf16 pairs

    for (int ph = 0; ph < 6; ++ph) {
        long r0 = (long)bm * 256 + arow;
        long r1 = r0 + 128;
        if (ph >= 2) {
            r0 = adj[r0 * 4 + (ph - 2)];
            r1 = adj[r1 * 4 + (ph - 2)];
        }
        const u16* pa0 = xbf + r0 * 512 + acol8;
        const u16* pa1 = xbf + r1 * 512 + acol8;
        const u16* bw = (ph == 0) ? wqT : wkT + (size_t)(ph - 1) * 262144;
        const u16* pb = bw + ((long)bn * 128 + arow) * 512 + acol8;

        auto STAGE = [&](int buf) {
            char* a = sAc + buf * 16384;
            g2l16(pa0, a + dst);
            g2l16(pa1, a + 8192 + dst);
            g2l16(pb, sBc + buf * 8192 + dst);
            pa0 += 32; pa1 += 32; pb += 32;
        };

        STAGE(0); STAGE(1);
        VM3; BAR; SCB;

        f32x4 acc[4][4] = {};
        int cur = 0, nx2 = 2;
        for (int t = 0; t < 16; ++t) {
            if (t + 2 < 16) STAGE(nx2);
            bf16x8 af[4], bfr[4];
            const char* rac = ra + cur * 16384;
            const char* rbc = rb + cur * 8192;
            #pragma unroll
            for (int mi = 0; mi < 4; ++mi) af[mi] = *(const bf16x8*)(rac + mi * 1024);
            #pragma unroll
            for (int ni = 0; ni < 4; ++ni) bfr[ni] = *(const bf16x8*)(rbc + ni * 1024);
            __builtin_amdgcn_s_setprio(1);
            #pragma unroll
            for (int mi = 0; mi < 4; ++mi)
                #pragma unroll
                for (int ni = 0; ni < 4; ++ni)
                    acc[mi][ni] = __builtin_amdgcn_mfma_f32_16x16x32_bf16(af[mi], bfr[ni], acc[mi][ni], 0, 0, 0);
            __builtin_amdgcn_s_setprio(0);
            if (t + 2 < 16)      { VM3; }
            else if (t + 1 < 16) { VM0; }
            BAR; SCB;
            cur = (cur == 2) ? 0 : cur + 1;
            nx2 = (nx2 == 2) ? 0 : nx2 + 1;
        }

        if (ph == 0) {
            #pragma unroll
            for (int mi = 0; mi < 4; ++mi)
                #pragma unroll
                for (int ni = 0; ni < 4; ++ni)
                    #pragma unroll
                    for (int jj = 0; jj < 2; ++jj)
                        qp[mi][ni][jj] = (unsigned)f2bu(acc[mi][ni][2 * jj])
                                       | ((unsigned)f2bu(acc[mi][ni][2 * jj + 1]) << 16);
        } else {
            int sc = h * 5 + (ph - 1);
            #pragma unroll
            for (int mi = 0; mi < 4; ++mi) {
                float pj[4];
                #pragma unroll
                for (int j = 0; j < 4; ++j) {
                    float s = 0.f;
                    #pragma unroll
                    for (int ni = 0; ni < 4; ++ni) {
                        unsigned w = qp[mi][ni][j >> 1];
                        u16 qh = (j & 1) ? (u16)(w >> 16) : (u16)(w & 0xffff);
                        s += acc[mi][ni][j] * bs2f((short)qh);
                    }
                    #pragma unroll
                    for (int m = 1; m < 16; m <<= 1) s += __shfl_xor(s, m);
                    pj[j] = s * 0.125f;
                }
                if (fr == 0) {
                    float4 o; o.x = pj[0]; o.y = pj[1]; o.z = pj[2]; o.w = pj[3];
                    *(float4*)&S[(size_t)sc * NND + rowbase + mi * 16 + g4 * 4] = o;
                }
            }
        }
    }
}

// Per-(h,r) column logsumexp over the node axis. S layout [40][N].
__global__ void k_colstats(const float* __restrict__ S, float* __restrict__ stats)
{
    int col = blockIdx.x;     // 0..39
    int tid = threadIdx.x;
    const float* Sc = S + (size_t)col * NND;
    float m = -1e30f, s = 0.f;
    for (int n = tid; n < NND; n += 256) {
        float v = Sc[n];
        if (v > m) { s = s * __expf(m - v) + 1.f; m = v; }
        else s += __expf(v - m);
    }
    __shared__ float smx[256], ssm[256];
    smx[tid] = m; ssm[tid] = s;
    __syncthreads();
    for (int off = 128; off; off >>= 1) {
        if (tid < off) {
            float m2 = smx[tid + off], s2 = ssm[tid + off];
            float M = fmaxf(smx[tid], m2);
            ssm[tid] = ssm[tid] * __expf(smx[tid] - M) + s2 * __expf(m2 - M);
            smx[tid] = M;
        }
        __syncthreads();
    }
    if (tid == 0) stats[col] = smx[0] + __logf(ssm[0]);   // logsumexp L
}

// ---------------------------------------------------------------------------
// Fused attention pass B: 5 V_r phases Horner-accumulated in the MFMA
// accumulator. Epilogue: t0 = xbf + Z (bf16). 256x128 tile, 8 waves.
// ---------------------------------------------------------------------------
__global__ __launch_bounds__(512, 2)
void k_attnVZ(const u16* __restrict__ xbf, const u16* __restrict__ wvT,
              const int* __restrict__ adj, const float* __restrict__ S,
              const float* __restrict__ stats, u16* __restrict__ t0)
{
    __shared__ u16 sA[3][8192];
    __shared__ u16 sB[3][4096];
    const int tid = threadIdx.x;
    const int wave = tid >> 6, lane = tid & 63;
    int bm, bn;
    xcd_decode(2, bm, bn);
    const int arow = tid >> 2;
    const int acol8 = ((tid & 3) ^ ((tid >> 3) & 3)) * 8;

    char* sAc = (char*)sA;
    char* sBc = (char*)sB;
    const int dst = tid * 16;

    const int wm = wave >> 1, wn = wave & 1;
    const int fr = lane & 15;
    const int g4 = lane >> 4;
    const int kbs = (g4 ^ ((fr >> 1) & 3)) * 16;
    const char* ra = sAc + (wm * 64 + fr) * 64 + kbs;
    const char* rb = sBc + (wn * 64 + fr) * 64 + kbs;

    const int h = bn * 2 + wn;
    const int rowbase = bm * 256 + wm * 64;

    f32x4 acc[4][4] = {};

    for (int ph = 0; ph < 5; ++ph) {
        long r0 = (long)bm * 256 + arow;
        long r1 = r0 + 128;
        if (ph >= 1) {
            r0 = adj[r0 * 4 + (ph - 1)];
            r1 = adj[r1 * 4 + (ph - 1)];
        }
        const u16* pa0 = xbf + r0 * 512 + acol8;
        const u16* pa1 = xbf + r1 * 512 + acol8;
        const u16* pb = wvT + (size_t)ph * 262144 + ((long)bn * 128 + arow) * 512 + acol8;

        auto STAGE = [&](int buf) {
            char* a = sAc + buf * 16384;
            g2l16(pa0, a + dst);
            g2l16(pa1, a + 8192 + dst);
            g2l16(pb, sBc + buf * 8192 + dst);
            pa0 += 32; pa1 += 32; pb += 32;
        };

        STAGE(0); STAGE(1);
        VM3; BAR; SCB;

        int cur = 0, nx2 = 2;
        for (int t = 0; t < 16; ++t) {
            if (t + 2 < 16) STAGE(nx2);
            bf16x8 af[4], bfr[4];
            const char* rac = ra + cur * 16384;
            const char* rbc = rb + cur * 8192;
            #pragma unroll
            for (int mi = 0; mi < 4; ++mi) af[mi] = *(const bf16x8*)(rac + mi * 1024);
            #pragma unroll
            for (int ni = 0; ni < 4; ++ni) bfr[ni] = *(const bf16x8*)(rbc + ni * 1024);
            __builtin_amdgcn_s_setprio(1);
            #pragma unroll
            for (int mi = 0; mi < 4; ++mi)
                #pragma unroll
                for (int ni = 0; ni < 4; ++ni)
                    acc[mi][ni] = __builtin_amdgcn_mfma_f32_16x16x32_bf16(af[mi], bfr[ni], acc[mi][ni], 0, 0, 0);
            __builtin_amdgcn_s_setprio(0);
            if (t + 2 < 16)      { VM3; }
            else if (t + 1 < 16) { VM0; }
            BAR; SCB;
            cur = (cur == 2) ? 0 : cur + 1;
            nx2 = (nx2 == 2) ? 0 : nx2 + 1;
        }

        int sc = h * 5 + ph;
        if (ph < 4) {
            // Horner: acc *= a_ph / a_{ph+1}
            float Lc = stats[sc], Ln = stats[sc + 1];
            #pragma unroll
            for (int mi = 0; mi < 4; ++mi) {
                int rb4 = rowbase + mi * 16 + g4 * 4;
                float4 c4 = *(const float4*)&S[(size_t)sc * NND + rb4];
                float4 n4 = *(const float4*)&S[(size_t)(sc + 1) * NND + rb4];
                float rt[4];
                rt[0] = __expf((c4.x - Lc) - (n4.x - Ln));
                rt[1] = __expf((c4.y - Lc) - (n4.y - Ln));
                rt[2] = __expf((c4.z - Lc) - (n4.z - Ln));
                rt[3] = __expf((c4.w - Lc) - (n4.w - Ln));
                #pragma unroll
                for (int ni = 0; ni < 4; ++ni)
                    #pragma unroll
                    for (int j = 0; j < 4; ++j)
                        acc[mi][ni][j] *= rt[j];
            }
        } else {
            // final scale by a_4 and write t0 = xbf + Z
            float Lc = stats[sc];
            #pragma unroll
            for (int mi = 0; mi < 4; ++mi) {
                int rb4 = rowbase + mi * 16 + g4 * 4;
                float4 c4 = *(const float4*)&S[(size_t)sc * NND + rb4];
                float a[4];
                a[0] = __expf(c4.x - Lc);
                a[1] = __expf(c4.y - Lc);
                a[2] = __expf(c4.z - Lc);
                a[3] = __expf(c4.w - Lc);
                #pragma unroll
                for (int ni = 0; ni < 4; ++ni) {
                    int col = bn * 128 + wn * 64 + ni * 16 + fr;
                    #pragma unroll
                    for (int j = 0; j < 4; ++j) {
                        long row = rb4 + j;
                        float v = acc[mi][ni][j] * a[j] + bs2f(xbf[row * 512 + col]);
                        t0[row * 512 + col] = f2bu(v);
                    }
                }
            }
        }
    }
}

// xbf = bf16(LayerNorm(t0) * g + b). block=128 (1 row)
__global__ void k_ln(const u16* __restrict__ t, u16* __restrict__ x,
                     const float* __restrict__ g, const float* __restrict__ b)
{
    int n = blockIdx.x, tid = threadIdx.x;
    long base = (long)n * 512 + tid * 4;
    s4v tv = *(const s4v*)(t + base);
    float v0 = bs2f(tv[0]), v1 = bs2f(tv[1]), v2 = bs2f(tv[2]), v3 = bs2f(tv[3]);
    float s1 = v0 + v1 + v2 + v3;
    float s2 = v0 * v0 + v1 * v1 + v2 * v2 + v3 * v3;
    #pragma unroll
    for (int off = 32; off; off >>= 1) {
        s1 += __shfl_down(s1, off);
        s2 += __shfl_down(s2, off);
    }
    __shared__ float a1[2], a2[2];
    int w = tid >> 6, lane = tid & 63;
    if (lane == 0) { a1[w] = s1; a2[w] = s2; }
    __syncthreads();
    float S1 = a1[0] + a1[1], S2 = a2[0] + a2[1];
    float mu = S1 * (1.f / 512.f);
    float var = S2 * (1.f / 512.f) - mu * mu;
    float rs = rsqrtf(var + 1e-5f);
    int c = tid * 4;
    s4v ob;
    ob[0] = (short)f2bu((v0 - mu) * rs * g[c] + b[c]);
    ob[1] = (short)f2bu((v1 - mu) * rs * g[c + 1] + b[c + 1]);
    ob[2] = (short)f2bu((v2 - mu) * rs * g[c + 2] + b[c + 2]);
    ob[3] = (short)f2bu((v3 - mu) * rs * g[c + 3] + b[c + 3]);
    *(s4v*)(x + base) = ob;
}

// Policy second GEMM: out[n,0..9] = p1[n,:1024] @ pol_w2 + b2 (chunk-local n).
__global__ void k_pol2(const u16* __restrict__ p1, const float* __restrict__ w2,
                       const float* __restrict__ b2, float* __restrict__ out)
{
    __shared__ float sw[10240];
    int tid = threadIdx.x;
    for (int i = tid; i < 10240; i += 256) sw[i] = w2[i];
    __syncthreads();
    int wv = tid >> 6, lane = tid & 63;
    for (int i = 0; i < 16; ++i) {
        int n = blockIdx.x * 64 + wv * 16 + i;
        const s8v* p = (const s8v*)(p1 + (long)n * 1024 + lane * 16);
        s8v v0 = p[0], v1 = p[1];
        float acc[10];
        #pragma unroll
        for (int m = 0; m < 10; ++m) acc[m] = 0.f;
        #pragma unroll
        for (int j = 0; j < 8; ++j) {
            float f0 = bs2f(v0[j]); int k0 = lane * 16 + j;
            float f1 = bs2f(v1[j]); int k1 = k0 + 8;
            #pragma unroll
            for (int m = 0; m < 10; ++m)
                acc[m] += f0 * sw[k0 * 10 + m] + f1 * sw[k1 * 10 + m];
        }
        #pragma unroll
        for (int m = 0; m < 10; ++m) {
            float s = acc[m];
            #pragma unroll
            for (int off = 32; off; off >>= 1) s += __shfl_down(s, off);
            if (lane == 0) out[(long)n * 10 + m] = s + b2[m];
        }
    }
}

__global__ void k_offsets(const int* __restrict__ bs, int* __restrict__ offs)
{
    if (threadIdx.x == 0) {
        int acc = 0;
        for (int i = 0; i < 128; ++i) { offs[i] = acc; acc += bs[i]; }
        offs[128] = acc;
    }
}

// Segment mean-pool over bf16 residual. block=128, 4 cols/thread.
__global__ void k_pool(const u16* __restrict__ x, const int* __restrict__ offs,
                       const int* __restrict__ bs, float* __restrict__ pooled)
{
    int g = blockIdx.x, tid = threadIdx.x;
    int c = tid * 4;
    int r0 = offs[g], r1 = offs[g + 1];
    float a0 = 0.f, a1 = 0.f, a2 = 0.f, a3 = 0.f;
    for (int rr = r0; rr < r1; ++rr) {
        s4v v = *(const s4v*)(x + (long)rr * 512 + c);
        a0 += bs2f(v[0]); a1 += bs2f(v[1]); a2 += bs2f(v[2]); a3 += bs2f(v[3]);
    }
    float d = fmaxf((float)bs[g], 1e-9f);
    pooled[g * 512 + c] = a0 / d;
    pooled[g * 512 + c + 1] = a1 / d;
    pooled[g * 512 + c + 2] = a2 / d;
    pooled[g * 512 + c + 3] = a3 / d;
}

__global__ void k_val1(const float* __restrict__ pooled, const float* __restrict__ w1,
                       const float* __restrict__ b1, float* __restrict__ v1)
{
    int g = blockIdx.x;
    int j = blockIdx.y * 256 + threadIdx.x;
    __shared__ float sp[512];
    for (int i = threadIdx.x; i < 512; i += 256) sp[i] = pooled[g * 512 + i];
    __syncthreads();
    float a = b1[j];
    for (int d = 0; d < 512; ++d) a += sp[d] * w1[(long)d * 1024 + j];
    v1[g * 1024 + j] = fmaxf(a, 0.f);
}

__global__ void k_val2(const float* __restrict__ v1, const float* __restrict__ w2,
                       const float* __restrict__ b2, float* __restrict__ out)
{
    int g = blockIdx.x, lane = threadIdx.x;
    float a = 0.f;
    for (int k = lane; k < 1024; k += 64) a += v1[g * 1024 + k] * w2[k];
    #pragma unroll
    for (int off = 32; off; off >>= 1) a += __shfl_down(a, off);
    if (lane == 0) out[(long)NND * 10 + g] = tanhf(a + b2[0]);
}

// ---------------------------------------------------------------------------
extern "C" void kernel_launch(void* const* d_in, const int* in_sizes, int n_in,
                              void* d_out, int out_size, void* d_ws, size_t ws_size,
                              hipStream_t stream)
{
    (void)in_sizes; (void)n_in; (void)out_size; (void)ws_size;
    const float* x6        = (const float*)d_in[0];
    const int*   adjacency = (const int*)d_in[1];
    const int*   batch_sz  = (const int*)d_in[2];
    const float* embed_w   = (const float*)d_in[3];
    const float* embed_b   = (const float*)d_in[4];
    const float* wq        = (const float*)d_in[5];
    const float* wk        = (const float*)d_in[6];
    const float* wv        = (const float*)d_in[7];
    const float* ffn_w1    = (const float*)d_in[8];
    const float* ffn_b1    = (const float*)d_in[9];
    const float* ffn_w2    = (const float*)d_in[10];
    const float* ffn_b2    = (const float*)d_in[11];
    const float* ln1_g     = (const float*)d_in[12];
    const float* ln1_b     = (const float*)d_in[13];
    const float* ln2_g     = (const float*)d_in[14];
    const float* ln2_b     = (const float*)d_in[15];
    const float* pol_w1    = (const float*)d_in[16];
    const float* pol_b1    = (const float*)d_in[17];
    const float* pol_w2    = (const float*)d_in[18];
    const float* pol_b2    = (const float*)d_in[19];
    const float* val_w1    = (const float*)d_in[20];
    const float* val_b1    = (const float*)d_in[21];
    const float* val_w2    = (const float*)d_in[22];
    const float* val_b2    = (const float*)d_in[23];
    float* out = (float*)d_out;

    char* ws = (char*)d_ws;
    size_t off = 0;
    auto alloc = [&](size_t bytes) {
        char* p = ws + off;
        off = (off + bytes + 255) & ~(size_t)255;
        return p;
    };
    // ~212 MB total (round-2-proven budget)
    u16*   xbf  = (u16*)  alloc((size_t)NND * 512 * 2);      // 64 MB residual
    u16*   t0   = (u16*)  alloc((size_t)NND * 512 * 2);      // 64 MB x+Z / x+f
    char*  arena=         alloc((size_t)CH * 2048 * 2);      // 64 MB (hb | p1)
    float* S    = (float*)alloc((size_t)40 * NND * 4);       // 10.5 MB scores [40][N]
    float* stats= (float*)alloc(4096);
    float* pooled=(float*)alloc(128 * 512 * 4);
    float* v1   = (float*)alloc(128 * 1024 * 4);
    int*   offs = (int*)  alloc(1024);
    u16*   wqTl = (u16*)  alloc((size_t)262144 * 2);         // per-layer slabs
    u16*   wkTl = (u16*)  alloc((size_t)5 * 262144 * 2);
    u16*   wvTl = (u16*)  alloc((size_t)5 * 262144 * 2);
    u16*   w1Tl = (u16*)  alloc((size_t)2048 * 512 * 2);
    u16*   w2Tl = (u16*)  alloc((size_t)512 * 2048 * 2);
    u16*   pw1T = (u16*)  alloc((size_t)1024 * 512 * 2);

    u16* hb  = (u16*)arena;     // CH x 2048
    u16* p1c = (u16*)arena;     // CH x 1024

    k_convT<<<512, 256, 0, stream>>>(pol_w1, pw1T, 512, 1024);
    k_offsets<<<1, 128, 0, stream>>>(batch_sz, offs);
    k_embed<<<NND, 512, 0, stream>>>(x6, embed_w, embed_b, xbf);

    for (int l = 0; l < 4; ++l) {
        k_conv_qkv<<<dim3(16, 88), 256, 0, stream>>>(wq, wk, wv, wqTl, wkTl, wvTl, l);
        k_convT<<<1024, 256, 0, stream>>>(ffn_w1 + (size_t)l * 512 * 2048, w1Tl, 512, 2048);
        k_convT<<<1024, 256, 0, stream>>>(ffn_w2 + (size_t)l * 2048 * 512, w2Tl, 2048, 512);

        k_attnKS<<<1024, 512, 0, stream>>>(xbf, wqTl, wkTl, adjacency, S);
        k_colstats<<<40, 256, 0, stream>>>(S, stats);
        k_attnVZ<<<1024, 512, 0, stream>>>(xbf, wvTl, adjacency, S, stats, t0);
        k_ln<<<NND, 128, 0, stream>>>(t0, xbf, ln1_g + l * 512, ln1_b + l * 512);
        for (int c = 0; c < NND / CH; ++c) {
            size_t row0 = (size_t)c * CH;
            k_gemm<true,true,false><<<1024, 512, 0, stream>>>(
                xbf + row0 * 512, w1Tl, hb, ffn_b1 + l * 2048, nullptr, 512, 2048, 4);
            k_gemm<true,false,true><<<256, 512, 0, stream>>>(
                hb, w2Tl, t0 + row0 * 512, ffn_b2 + l * 512, xbf + row0 * 512, 2048, 512, 2);
        }
        k_ln<<<NND, 128, 0, stream>>>(t0, xbf, ln2_g + l * 512, ln2_b + l * 512);
    }

    // Policy head per row-chunk
    for (int c = 0; c < NND / CH; ++c) {
        size_t row0 = (size_t)c * CH;
        k_gemm<true,true,false><<<512, 512, 0, stream>>>(
            xbf + row0 * 512, pw1T, p1c, pol_b1, nullptr, 512, 1024, 3);
        k_pol2<<<CH / 64, 256, 0, stream>>>(p1c, pol_w2, pol_b2, out + row0 * 10);
    }
    // Value head
    k_pool<<<128, 128, 0, stream>>>(xbf, offs, batch_sz, pooled);
    k_val1<<<dim3(128, 4), 256, 0, stream>>>(pooled, val_w1, val_b1, v1);
    k_val2<<<128, 64, 0, stream>>>(v1, val_w2, val_b2, out);
}

// Round 9
// 4923.408 us; speedup vs baseline: 1.0894x; 1.0894x over previous
//
#include <hip/hip_runtime.h>

typedef unsigned short u16;
typedef __bf16 bf16x8 __attribute__((ext_vector_type(8)));
typedef float f32x4 __attribute__((ext_vector_type(4)));
typedef short s8v __attribute__((ext_vector_type(8)));
typedef short s4v __attribute__((ext_vector_type(4)));

#define NND 65536   // nodes
#define CHF 32768   // FFN/policy row-chunk (hb spans t0+arena = 128 MB)

#define VM2 asm volatile("s_waitcnt vmcnt(2)" ::: "memory")
#define VM0 asm volatile("s_waitcnt vmcnt(0)" ::: "memory")
#define BAR __builtin_amdgcn_s_barrier()
#define SCB __builtin_amdgcn_sched_barrier(0)

__device__ __forceinline__ float bs2f(short s) {
    union { unsigned u; float f; } x;
    x.u = ((unsigned)(u16)s) << 16;
    return x.f;
}
__device__ __forceinline__ u16 f2bu(float f) {
    union { float f; unsigned u; } x;
    x.f = f;
    unsigned r = x.u + 0x7FFFu + ((x.u >> 16) & 1u);
    return (u16)(r >> 16);
}
__device__ __forceinline__ void g2l16(const void* g, void* l) {
    __builtin_amdgcn_global_load_lds((const __attribute__((address_space(1))) void*)g,
                                     (__attribute__((address_space(3))) void*)l, 16, 0, 0);
}
// grouped XCD swizzle: all col-blocks (bn) of a row-tile (bm) land on one XCD
__device__ __forceinline__ void xcd_decode(int lognbn, int& bm, int& bn) {
    int flat = blockIdx.x;
    int cpx = gridDim.x >> 3;
    int virt = (flat & 7) * cpx + (flat >> 3);
    bm = virt >> lognbn;
    bn = virt & ((1 << lognbn) - 1);
}

// ---------------------------------------------------------------------------
// Per-layer wq/wk/wv conversion: fp32 (512x64) -> bf16 transposed (64x512).
// ---------------------------------------------------------------------------
__global__ void k_conv_qkv(const float* __restrict__ wq, const float* __restrict__ wk,
                           const float* __restrict__ wv, u16* __restrict__ wqT,
                           u16* __restrict__ wkT, u16* __restrict__ wvT, int l)
{
    int bz = blockIdx.y;
    const float* in; u16* out;
    if (bz < 40) {
        int h = bz / 5, r = bz % 5;
        in  = wk + (size_t)((l * 8 + h) * 5 + r) * 32768;
        out = wkT + (size_t)r * 262144 + h * 64 * 512;
    } else if (bz < 80) {
        int t = bz - 40; int h = t / 5, r = t % 5;
        in  = wv + (size_t)((l * 8 + h) * 5 + r) * 32768;
        out = wvT + (size_t)r * 262144 + h * 64 * 512;
    } else {
        int h = bz - 80;
        in  = wq + (size_t)(l * 8 + h) * 32768;
        out = wqT + h * 64 * 512;
    }
    int d0 = blockIdx.x * 32;
    __shared__ float s[32][65];
    int tid = threadIdx.x;
    int di = tid >> 3, k8 = (tid & 7) * 8;
    const float* ip = in + (long)(d0 + di) * 64 + k8;
    #pragma unroll
    for (int i = 0; i < 8; ++i) s[di][k8 + i] = ip[i];
    __syncthreads();
    int kk = tid >> 2, d8 = (tid & 3) * 8;
    s8v o;
    #pragma unroll
    for (int i = 0; i < 8; ++i) o[i] = (short)f2bu(s[d8 + i][kk]);
    *(s8v*)(out + (long)kk * 512 + d0 + d8) = o;
}

// Generic transpose: in (R x C fp32) -> out (C x R bf16). grid = (R/32)*(C/32).
__global__ void k_convT(const float* __restrict__ in, u16* __restrict__ out, int R, int C)
{
    int tiles_c = C >> 5;
    int tr = blockIdx.x / tiles_c, tc = blockIdx.x % tiles_c;
    int r0 = tr * 32, c0 = tc * 32;
    __shared__ float s[32][33];
    int tid = threadIdx.x;
    int ri = tid >> 3, c4 = (tid & 7) * 4;
    const float4 v = *(const float4*)(in + (long)(r0 + ri) * C + c0 + c4);
    s[ri][c4] = v.x; s[ri][c4 + 1] = v.y; s[ri][c4 + 2] = v.z; s[ri][c4 + 3] = v.w;
    __syncthreads();
    int ci = tid >> 3, r4 = (tid & 7) * 4;
    s4v o;
    #pragma unroll
    for (int i = 0; i < 4; ++i) o[i] = (short)f2bu(s[r4 + i][ci]);
    *(s4v*)(out + (long)(c0 + ci) * R + r0 + r4) = o;
}

// ---------------------------------------------------------------------------
// Embed: xbf = bf16(x6 @ embed_w + embed_b). block=512 (one row per block)
// ---------------------------------------------------------------------------
__global__ void k_embed(const float* __restrict__ x6, const float* __restrict__ ew,
                        const float* __restrict__ eb, u16* __restrict__ xbf)
{
    int n = blockIdx.x, j = threadIdx.x;
    const float* r = x6 + (long)n * 6;
    float a = eb[j] + r[0] * ew[j] + r[1] * ew[512 + j] + r[2] * ew[1024 + j]
            + r[3] * ew[1536 + j] + r[4] * ew[2048 + j] + r[5] * ew[2560 + j];
    xbf[(long)n * 512 + j] = f2bu(a);
}

// ---------------------------------------------------------------------------
// bf16 MFMA GEMM: 128x128 tile, BK=32, 512 threads / 8 waves (4x2, wave tile
// 32x64), bank-conflict swizzle, 3-buffer LDS pipeline, counted vmcnt,
// setprio. BT = Ncols x K row-major. grouped-XCD 1-D grid.  (round-7 proven)
// ---------------------------------------------------------------------------
template<bool BIAS, bool RELU, bool ADDX>
__global__ __launch_bounds__(512, 4)
void k_gemm(const u16* __restrict__ A, const u16* __restrict__ BT,
            u16* __restrict__ C, const float* __restrict__ bias,
            const u16* __restrict__ resid, int K, int Ncols, int lognbn)
{
    __shared__ u16 sA[3][4096];
    __shared__ u16 sB[3][4096];
    const int tid = threadIdx.x;
    const int wave = tid >> 6, lane = tid & 63;
    int bm, bn;
    xcd_decode(lognbn, bm, bn);

    const int arow = tid >> 2;                              // 0..127
    const int acol8 = ((tid & 3) ^ ((tid >> 3) & 3)) * 8;   // source pre-swizzle
    const u16* pa = A + ((long)bm * 128 + arow) * K + acol8;
    const u16* pb = BT + ((long)bn * 128 + arow) * K + acol8;

    char* sAc = (char*)sA;
    char* sBc = (char*)sB;
    const int dst = tid * 16;

    f32x4 acc[2][4] = {};

    const int wm = wave >> 1, wn = wave & 1;                // 4x2 wave grid
    const int fr = lane & 15;
    const int g4 = lane >> 4;
    const int kbs = (g4 ^ ((fr >> 1) & 3)) * 16;            // swizzled read slot
    const char* ra = sAc + (wm * 32 + fr) * 64 + kbs;
    const char* rb = sBc + (wn * 64 + fr) * 64 + kbs;

    auto STAGE = [&](int buf) {
        g2l16(pa, sAc + buf * 8192 + dst);
        g2l16(pb, sBc + buf * 8192 + dst);
        pa += 32; pb += 32;
    };

    const int NT = K >> 5;
    STAGE(0); STAGE(1);
    VM2; BAR; SCB;

    int cur = 0, nx2 = 2;
    for (int t = 0; t < NT; ++t) {
        if (t + 2 < NT) STAGE(nx2);
        bf16x8 af[2], bfr[4];
        const char* rac = ra + cur * 8192;
        const char* rbc = rb + cur * 8192;
        #pragma unroll
        for (int mi = 0; mi < 2; ++mi) af[mi] = *(const bf16x8*)(rac + mi * 1024);
        #pragma unroll
        for (int ni = 0; ni < 4; ++ni) bfr[ni] = *(const bf16x8*)(rbc + ni * 1024);
        __builtin_amdgcn_s_setprio(1);
        #pragma unroll
        for (int mi = 0; mi < 2; ++mi)
            #pragma unroll
            for (int ni = 0; ni < 4; ++ni)
                acc[mi][ni] = __builtin_amdgcn_mfma_f32_16x16x32_bf16(af[mi], bfr[ni], acc[mi][ni], 0, 0, 0);
        __builtin_amdgcn_s_setprio(0);
        if (t + 2 < NT)      { VM2; }
        else if (t + 1 < NT) { VM0; }
        BAR; SCB;
        cur = (cur == 2) ? 0 : cur + 1;
        nx2 = (nx2 == 2) ? 0 : nx2 + 1;
    }

    const int crow0 = bm * 128 + wm * 32 + g4 * 4;
    const int ccol0 = bn * 128 + wn * 64 + fr;
    #pragma unroll
    for (int mi = 0; mi < 2; ++mi) {
        #pragma unroll
        for (int ni = 0; ni < 4; ++ni) {
            int col = ccol0 + ni * 16;
            float bv = BIAS ? bias[col] : 0.f;
            #pragma unroll
            for (int j = 0; j < 4; ++j) {
                int row = crow0 + mi * 16 + j;
                float v = acc[mi][ni][j] + bv;
                if (ADDX) v += bs2f(resid[(long)row * Ncols + col]);
                if (RELU) v = fmaxf(v, 0.f);
                C[(long)row * Ncols + col] = f2bu(v);
            }
        }
    }
}

// ---------------------------------------------------------------------------
// Fused attention pass A: phase 0 computes Q tile (registers, packed bf16),
// phases 1..5 compute K_r; S[h*5+r][n] = 0.125*dot64(Q,K) via elementwise
// frag product + 16-lane shfl reduce. 512 thr / 8 waves, pipelined K-loop.
// ---------------------------------------------------------------------------
__global__ __launch_bounds__(512, 4)
void k_attnKS(const u16* __restrict__ xbf, const u16* __restrict__ wqT,
              const u16* __restrict__ wkT, const int* __restrict__ adj,
              float* __restrict__ S)
{
    __shared__ u16 sA[3][4096];
    __shared__ u16 sB[3][4096];
    const int tid = threadIdx.x;
    const int wave = tid >> 6, lane = tid & 63;
    int bm, bn;
    xcd_decode(2, bm, bn);
    const int arow = tid >> 2;
    const int acol8 = ((tid & 3) ^ ((tid >> 3) & 3)) * 8;

    char* sAc = (char*)sA;
    char* sBc = (char*)sB;
    const int dst = tid * 16;

    const int wm = wave >> 1, wn = wave & 1;
    const int fr = lane & 15;
    const int g4 = lane >> 4;
    const int kbs = (g4 ^ ((fr >> 1) & 3)) * 16;
    const char* ra = sAc + (wm * 32 + fr) * 64 + kbs;
    const char* rb = sBc + (wn * 64 + fr) * 64 + kbs;

    const int h = bn * 2 + wn;
    const int rowbase = bm * 128 + wm * 32;

    unsigned qp[2][4][2];   // Q fragments, packed bf16 pairs

    for (int ph = 0; ph < 6; ++ph) {
        long r0 = (long)bm * 128 + arow;
        if (ph >= 2) r0 = adj[r0 * 4 + (ph - 2)];
        const u16* pa = xbf + r0 * 512 + acol8;
        const u16* bw = (ph == 0) ? wqT : wkT + (size_t)(ph - 1) * 262144;
        const u16* pb = bw + ((long)bn * 128 + arow) * 512 + acol8;

        auto STAGE = [&](int buf) {
            g2l16(pa, sAc + buf * 8192 + dst);
            g2l16(pb, sBc + buf * 8192 + dst);
            pa += 32; pb += 32;
        };

        STAGE(0); STAGE(1);
        VM2; BAR; SCB;

        f32x4 acc[2][4] = {};
        int cur = 0, nx2 = 2;
        for (int t = 0; t < 16; ++t) {
            if (t + 2 < 16) STAGE(nx2);
            bf16x8 af[2], bfr[4];
            const char* rac = ra + cur * 8192;
            const char* rbc = rb + cur * 8192;
            #pragma unroll
            for (int mi = 0; mi < 2; ++mi) af[mi] = *(const bf16x8*)(rac + mi * 1024);
            #pragma unroll
            for (int ni = 0; ni < 4; ++ni) bfr[ni] = *(const bf16x8*)(rbc + ni * 1024);
            __builtin_amdgcn_s_setprio(1);
            #pragma unroll
            for (int mi = 0; mi < 2; ++mi)
                #pragma unroll
                for (int ni = 0; ni < 4; ++ni)
                    acc[mi][ni] = __builtin_amdgcn_mfma_f32_16x16x32_bf16(af[mi], bfr[ni], acc[mi][ni], 0, 0, 0);
            __builtin_amdgcn_s_setprio(0);
            if (t + 2 < 16)      { VM2; }
            else if (t + 1 < 16) { VM0; }
            BAR; SCB;
            cur = (cur == 2) ? 0 : cur + 1;
            nx2 = (nx2 == 2) ? 0 : nx2 + 1;
        }

        if (ph == 0) {
            #pragma unroll
            for (int mi = 0; mi < 2; ++mi)
                #pragma unroll
                for (int ni = 0; ni < 4; ++ni)
                    #pragma unroll
                    for (int jj = 0; jj < 2; ++jj)
                        qp[mi][ni][jj] = (unsigned)f2bu(acc[mi][ni][2 * jj])
                                       | ((unsigned)f2bu(acc[mi][ni][2 * jj + 1]) << 16);
        } else {
            int sc = h * 5 + (ph - 1);
            #pragma unroll
            for (int mi = 0; mi < 2; ++mi) {
                float pj[4];
                #pragma unroll
                for (int j = 0; j < 4; ++j) {
                    float s = 0.f;
                    #pragma unroll
                    for (int ni = 0; ni < 4; ++ni) {
                        unsigned w = qp[mi][ni][j >> 1];
                        u16 qh = (j & 1) ? (u16)(w >> 16) : (u16)(w & 0xffff);
                        s += acc[mi][ni][j] * bs2f((short)qh);
                    }
                    #pragma unroll
                    for (int m = 1; m < 16; m <<= 1) s += __shfl_xor(s, m);
                    pj[j] = s * 0.125f;
                }
                if (fr == 0) {
                    float4 o; o.x = pj[0]; o.y = pj[1]; o.z = pj[2]; o.w = pj[3];
                    *(float4*)&S[(size_t)sc * NND + rowbase + mi * 16 + g4 * 4] = o;
                }
            }
        }
    }
}

// Per-(h,r) column logsumexp over the node axis. S layout [40][N].
__global__ void k_colstats(const float* __restrict__ S, float* __restrict__ stats)
{
    int col = blockIdx.x;     // 0..39
    int tid = threadIdx.x;
    const float* Sc = S + (size_t)col * NND;
    float m = -1e30f, s = 0.f;
    for (int n = tid; n < NND; n += 256) {
        float v = Sc[n];
        if (v > m) { s = s * __expf(m - v) + 1.f; m = v; }
        else s += __expf(v - m);
    }
    __shared__ float smx[256], ssm[256];
    smx[tid] = m; ssm[tid] = s;
    __syncthreads();
    for (int off = 128; off; off >>= 1) {
        if (tid < off) {
            float m2 = smx[tid + off], s2 = ssm[tid + off];
            float M = fmaxf(smx[tid], m2);
            ssm[tid] = ssm[tid] * __expf(smx[tid] - M) + s2 * __expf(m2 - M);
            smx[tid] = M;
        }
        __syncthreads();
    }
    if (tid == 0) stats[col] = smx[0] + __logf(ssm[0]);   // logsumexp L
}

// ---------------------------------------------------------------------------
// Fused attention pass B: 5 V_r phases Horner-accumulated in the MFMA
// accumulator. Epilogue: t0 = xbf + Z (bf16). 512 thr / 8 waves, pipelined.
// ---------------------------------------------------------------------------
__global__ __launch_bounds__(512, 4)
void k_attnVZ(const u16* __restrict__ xbf, const u16* __restrict__ wvT,
              const int* __restrict__ adj, const float* __restrict__ S,
              const float* __restrict__ stats, u16* __restrict__ t0)
{
    __shared__ u16 sA[3][4096];
    __shared__ u16 sB[3][4096];
    const int tid = threadIdx.x;
    const int wave = tid >> 6, lane = tid & 63;
    int bm, bn;
    xcd_decode(2, bm, bn);
    const int arow = tid >> 2;
    const int acol8 = ((tid & 3) ^ ((tid >> 3) & 3)) * 8;

    char* sAc = (char*)sA;
    char* sBc = (char*)sB;
    const int dst = tid * 16;

    const int wm = wave >> 1, wn = wave & 1;
    const int fr = lane & 15;
    const int g4 = lane >> 4;
    const int kbs = (g4 ^ ((fr >> 1) & 3)) * 16;
    const char* ra = sAc + (wm * 32 + fr) * 64 + kbs;
    const char* rb = sBc + (wn * 64 + fr) * 64 + kbs;

    const int h = bn * 2 + wn;
    const int rowbase = bm * 128 + wm * 32;

    f32x4 acc[2][4] = {};

    for (int ph = 0; ph < 5; ++ph) {
        long r0 = (long)bm * 128 + arow;
        if (ph >= 1) r0 = adj[r0 * 4 + (ph - 1)];
        const u16* pa = xbf + r0 * 512 + acol8;
        const u16* pb = wvT + (size_t)ph * 262144 + ((long)bn * 128 + arow) * 512 + acol8;

        auto STAGE = [&](int buf) {
            g2l16(pa, sAc + buf * 8192 + dst);
            g2l16(pb, sBc + buf * 8192 + dst);
            pa += 32; pb += 32;
        };

        STAGE(0); STAGE(1);
        VM2; BAR; SCB;

        int cur = 0, nx2 = 2;
        for (int t = 0; t < 16; ++t) {
            if (t + 2 < 16) STAGE(nx2);
            bf16x8 af[2], bfr[4];
            const char* rac = ra + cur * 8192;
            const char* rbc = rb + cur * 8192;
            #pragma unroll
            for (int mi = 0; mi < 2; ++mi) af[mi] = *(const bf16x8*)(rac + mi * 1024);
            #pragma unroll
            for (int ni = 0; ni < 4; ++ni) bfr[ni] = *(const bf16x8*)(rbc + ni * 1024);
            __builtin_amdgcn_s_setprio(1);
            #pragma unroll
            for (int mi = 0; mi < 2; ++mi)
                #pragma unroll
                for (int ni = 0; ni < 4; ++ni)
                    acc[mi][ni] = __builtin_amdgcn_mfma_f32_16x16x32_bf16(af[mi], bfr[ni], acc[mi][ni], 0, 0, 0);
            __builtin_amdgcn_s_setprio(0);
            if (t + 2 < 16)      { VM2; }
            else if (t + 1 < 16) { VM0; }
            BAR; SCB;
            cur = (cur == 2) ? 0 : cur + 1;
            nx2 = (nx2 == 2) ? 0 : nx2 + 1;
        }

        int sc = h * 5 + ph;
        if (ph < 4) {
            // Horner: acc *= a_ph / a_{ph+1}
            float Lc = stats[sc], Ln = stats[sc + 1];
            #pragma unroll
            for (int mi = 0; mi < 2; ++mi) {
                int rb4 = rowbase + mi * 16 + g4 * 4;
                float4 c4 = *(const float4*)&S[(size_t)sc * NND + rb4];
                float4 n4 = *(const float4*)&S[(size_t)(sc + 1) * NND + rb4];
                float rt[4];
                rt[0] = __expf((c4.x - Lc) - (n4.x - Ln));
                rt[1] = __expf((c4.y - Lc) - (n4.y - Ln));
                rt[2] = __expf((c4.z - Lc) - (n4.z - Ln));
                rt[3] = __expf((c4.w - Lc) - (n4.w - Ln));
                #pragma unroll
                for (int ni = 0; ni < 4; ++ni)
                    #pragma unroll
                    for (int j = 0; j < 4; ++j)
                        acc[mi][ni][j] *= rt[j];
            }
        } else {
            // final scale by a_4 and write t0 = xbf + Z
            float Lc = stats[sc];
            #pragma unroll
            for (int mi = 0; mi < 2; ++mi) {
                int rb4 = rowbase + mi * 16 + g4 * 4;
                float4 c4 = *(const float4*)&S[(size_t)sc * NND + rb4];
                float a[4];
                a[0] = __expf(c4.x - Lc);
                a[1] = __expf(c4.y - Lc);
                a[2] = __expf(c4.z - Lc);
                a[3] = __expf(c4.w - Lc);
                #pragma unroll
                for (int ni = 0; ni < 4; ++ni) {
                    int col = bn * 128 + wn * 64 + ni * 16 + fr;
                    #pragma unroll
                    for (int j = 0; j < 4; ++j) {
                        long row = rb4 + j;
                        float v = acc[mi][ni][j] * a[j] + bs2f(xbf[row * 512 + col]);
                        t0[row * 512 + col] = f2bu(v);
                    }
                }
            }
        }
    }
}

// x = bf16(LayerNorm(t) * g + b). block=128 (1 row). Safe with t == x.
__global__ void k_ln(const u16* __restrict__ t, u16* __restrict__ x,
                     const float* __restrict__ g, const float* __restrict__ b)
{
    int n = blockIdx.x, tid = threadIdx.x;
    long base = (long)n * 512 + tid * 4;
    s4v tv = *(const s4v*)(t + base);
    float v0 = bs2f(tv[0]), v1 = bs2f(tv[1]), v2 = bs2f(tv[2]), v3 = bs2f(tv[3]);
    float s1 = v0 + v1 + v2 + v3;
    float s2 = v0 * v0 + v1 * v1 + v2 * v2 + v3 * v3;
    #pragma unroll
    for (int off = 32; off; off >>= 1) {
        s1 += __shfl_down(s1, off);
        s2 += __shfl_down(s2, off);
    }
    __shared__ float a1[2], a2[2];
    int w = tid >> 6, lane = tid & 63;
    if (lane == 0) { a1[w] = s1; a2[w] = s2; }
    __syncthreads();
    float S1 = a1[0] + a1[1], S2 = a2[0] + a2[1];
    float mu = S1 * (1.f / 512.f);
    float var = S2 * (1.f / 512.f) - mu * mu;
    float rs = rsqrtf(var + 1e-5f);
    int c = tid * 4;
    s4v ob;
    ob[0] = (short)f2bu((v0 - mu) * rs * g[c] + b[c]);
    ob[1] = (short)f2bu((v1 - mu) * rs * g[c + 1] + b[c + 1]);
    ob[2] = (short)f2bu((v2 - mu) * rs * g[c + 2] + b[c + 2]);
    ob[3] = (short)f2bu((v3 - mu) * rs * g[c + 3] + b[c + 3]);
    *(s4v*)(x + base) = ob;
}

// Policy second GEMM: out[n,0..9] = p1[n,:1024] @ pol_w2 + b2 (chunk-local n).
__global__ void k_pol2(const u16* __restrict__ p1, const float* __restrict__ w2,
                       const float* __restrict__ b2, float* __restrict__ out)
{
    __shared__ float sw[10240];
    int tid = threadIdx.x;
    for (int i = tid; i < 10240; i += 256) sw[i] = w2[i];
    __syncthreads();
    int wv = tid >> 6, lane = tid & 63;
    for (int i = 0; i < 16; ++i) {
        int n = blockIdx.x * 64 + wv * 16 + i;
        const s8v* p = (const s8v*)(p1 + (long)n * 1024 + lane * 16);
        s8v v0 = p[0], v1 = p[1];
        float acc[10];
        #pragma unroll
        for (int m = 0; m < 10; ++m) acc[m] = 0.f;
        #pragma unroll
        for (int j = 0; j < 8; ++j) {
            float f0 = bs2f(v0[j]); int k0 = lane * 16 + j;
            float f1 = bs2f(v1[j]); int k1 = k0 + 8;
            #pragma unroll
            for (int m = 0; m < 10; ++m)
                acc[m] += f0 * sw[k0 * 10 + m] + f1 * sw[k1 * 10 + m];
        }
        #pragma unroll
        for (int m = 0; m < 10; ++m) {
            float s = acc[m];
            #pragma unroll
            for (int off = 32; off; off >>= 1) s += __shfl_down(s, off);
            if (lane == 0) out[(long)n * 10 + m] = s + b2[m];
        }
    }
}

__global__ void k_offsets(const int* __restrict__ bs, int* __restrict__ offs)
{
    if (threadIdx.x == 0) {
        int acc = 0;
        for (int i = 0; i < 128; ++i) { offs[i] = acc; acc += bs[i]; }
        offs[128] = acc;
    }
}

// Segment mean-pool over bf16 residual. block=128, 4 cols/thread.
__global__ void k_pool(const u16* __restrict__ x, const int* __restrict__ offs,
                       const int* __restrict__ bs, float* __restrict__ pooled)
{
    int g = blockIdx.x, tid = threadIdx.x;
    int c = tid * 4;
    int r0 = offs[g], r1 = offs[g + 1];
    float a0 = 0.f, a1 = 0.f, a2 = 0.f, a3 = 0.f;
    for (int rr = r0; rr < r1; ++rr) {
        s4v v = *(const s4v*)(x + (long)rr * 512 + c);
        a0 += bs2f(v[0]); a1 += bs2f(v[1]); a2 += bs2f(v[2]); a3 += bs2f(v[3]);
    }
    float d = fmaxf((float)bs[g], 1e-9f);
    pooled[g * 512 + c] = a0 / d;
    pooled[g * 512 + c + 1] = a1 / d;
    pooled[g * 512 + c + 2] = a2 / d;
    pooled[g * 512 + c + 3] = a3 / d;
}

__global__ void k_val1(const float* __restrict__ pooled, const float* __restrict__ w1,
                       const float* __restrict__ b1, float* __restrict__ v1)
{
    int g = blockIdx.x;
    int j = blockIdx.y * 256 + threadIdx.x;
    __shared__ float sp[512];
    for (int i = threadIdx.x; i < 512; i += 256) sp[i] = pooled[g * 512 + i];
    __syncthreads();
    float a = b1[j];
    for (int d = 0; d < 512; ++d) a += sp[d] * w1[(long)d * 1024 + j];
    v1[g * 1024 + j] = fmaxf(a, 0.f);
}

__global__ void k_val2(const float* __restrict__ v1, const float* __restrict__ w2,
                       const float* __restrict__ b2, float* __restrict__ out)
{
    int g = blockIdx.x, lane = threadIdx.x;
    float a = 0.f;
    for (int k = lane; k < 1024; k += 64) a += v1[g * 1024 + k] * w2[k];
    #pragma unroll
    for (int off = 32; off; off >>= 1) a += __shfl_down(a, off);
    if (lane == 0) out[(long)NND * 10 + g] = tanhf(a + b2[0]);
}

// ---------------------------------------------------------------------------
extern "C" void kernel_launch(void* const* d_in, const int* in_sizes, int n_in,
                              void* d_out, int out_size, void* d_ws, size_t ws_size,
                              hipStream_t stream)
{
    (void)in_sizes; (void)n_in; (void)out_size; (void)ws_size;
    const float* x6        = (const float*)d_in[0];
    const int*   adjacency = (const int*)d_in[1];
    const int*   batch_sz  = (const int*)d_in[2];
    const float* embed_w   = (const float*)d_in[3];
    const float* embed_b   = (const float*)d_in[4];
    const float* wq        = (const float*)d_in[5];
    const float* wk        = (const float*)d_in[6];
    const float* wv        = (const float*)d_in[7];
    const float* ffn_w1    = (const float*)d_in[8];
    const float* ffn_b1    = (const float*)d_in[9];
    const float* ffn_w2    = (const float*)d_in[10];
    const float* ffn_b2    = (const float*)d_in[11];
    const float* ln1_g     = (const float*)d_in[12];
    const float* ln1_b     = (const float*)d_in[13];
    const float* ln2_g     = (const float*)d_in[14];
    const float* ln2_b     = (const float*)d_in[15];
    const float* pol_w1    = (const float*)d_in[16];
    const float* pol_b1    = (const float*)d_in[17];
    const float* pol_w2    = (const float*)d_in[18];
    const float* pol_b2    = (const float*)d_in[19];
    const float* val_w1    = (const float*)d_in[20];
    const float* val_b1    = (const float*)d_in[21];
    const float* val_w2    = (const float*)d_in[22];
    const float* val_b2    = (const float*)d_in[23];
    float* out = (float*)d_out;

    char* ws = (char*)d_ws;
    size_t off = 0;
    auto alloc = [&](size_t bytes) {
        char* p = ws + off;
        off = (off + bytes + 255) & ~(size_t)255;
        return p;
    };
    // ~212 MB total (round-2-proven budget)
    u16*   xbf  = (u16*)  alloc((size_t)NND * 512 * 2);      // 64 MB residual
    u16*   t0   = (u16*)  alloc((size_t)NND * 512 * 2);      // 64 MB x+Z (dead during FFN)
    char*  arena=         alloc((size_t)NND * 512 * 2);      // 64 MB; t0+arena = 128 MB hb span
    float* S    = (float*)alloc((size_t)40 * NND * 4);       // 10.5 MB scores [40][N]
    float* stats= (float*)alloc(4096);
    float* pooled=(float*)alloc(128 * 512 * 4);
    float* v1   = (float*)alloc(128 * 1024 * 4);
    int*   offs = (int*)  alloc(1024);
    u16*   wqTl = (u16*)  alloc((size_t)262144 * 2);         // per-layer slabs
    u16*   wkTl = (u16*)  alloc((size_t)5 * 262144 * 2);
    u16*   wvTl = (u16*)  alloc((size_t)5 * 262144 * 2);
    u16*   w1Tl = (u16*)  alloc((size_t)2048 * 512 * 2);
    u16*   w2Tl = (u16*)  alloc((size_t)512 * 2048 * 2);
    u16*   pw1T = (u16*)  alloc((size_t)1024 * 512 * 2);

    u16* hb  = t0;              // CHF x 2048 bf16 = 128 MB, spans t0+arena
    u16* p1c = (u16*)arena;     // CHF x 1024 bf16 = 64 MB

    k_convT<<<512, 256, 0, stream>>>(pol_w1, pw1T, 512, 1024);
    k_offsets<<<1, 128, 0, stream>>>(batch_sz, offs);
    k_embed<<<NND, 512, 0, stream>>>(x6, embed_w, embed_b, xbf);

    for (int l = 0; l < 4; ++l) {
        k_conv_qkv<<<dim3(16, 88), 256, 0, stream>>>(wq, wk, wv, wqTl, wkTl, wvTl, l);
        k_convT<<<1024, 256, 0, stream>>>(ffn_w1 + (size_t)l * 512 * 2048, w1Tl, 512, 2048);
        k_convT<<<1024, 256, 0, stream>>>(ffn_w2 + (size_t)l * 2048 * 512, w2Tl, 2048, 512);

        k_attnKS<<<2048, 512, 0, stream>>>(xbf, wqTl, wkTl, adjacency, S);
        k_colstats<<<40, 256, 0, stream>>>(S, stats);
        k_attnVZ<<<2048, 512, 0, stream>>>(xbf, wvTl, adjacency, S, stats, t0);
        k_ln<<<NND, 128, 0, stream>>>(t0, xbf, ln1_g + l * 512, ln1_b + l * 512);
        // FFN: hb spans t0+arena (t0 dead here); w2 writes xbf in place.
        for (int c = 0; c < NND / CHF; ++c) {
            size_t row0 = (size_t)c * CHF;
            k_gemm<true,true,false><<<4096, 512, 0, stream>>>(
                xbf + row0 * 512, w1Tl, hb, ffn_b1 + l * 2048, nullptr, 512, 2048, 4);
            k_gemm<true,false,true><<<1024, 512, 0, stream>>>(
                hb, w2Tl, xbf + row0 * 512, ffn_b2 + l * 512, xbf + row0 * 512, 2048, 512, 2);
        }
        k_ln<<<NND, 128, 0, stream>>>(xbf, xbf, ln2_g + l * 512, ln2_b + l * 512);
    }

    // Policy head per row-chunk
    for (int c = 0; c < NND / CHF; ++c) {
        size_t row0 = (size_t)c * CHF;
        k_gemm<true,true,false><<<2048, 512, 0, stream>>>(
            xbf + row0 * 512, pw1T, p1c, pol_b1, nullptr, 512, 1024, 3);
        k_pol2<<<CHF / 64, 256, 0, stream>>>(p1c, pol_w2, pol_b2, out + row0 * 10);
    }
    // Value head
    k_pool<<<128, 128, 0, stream>>>(xbf, offs, batch_sz, pooled);
    k_val1<<<dim3(128, 4), 256, 0, stream>>>(pooled, val_w1, val_b1, v1);
    k_val2<<<128, 64, 0, stream>>>(v1, val_w2, val_b2, out);
}

// Round 10
// 4313.407 us; speedup vs baseline: 1.2435x; 1.1414x over previous
//
#include <hip/hip_runtime.h>

typedef unsigned short u16;
typedef __bf16 bf16x8 __attribute__((ext_vector_type(8)));
typedef float f32x4 __attribute__((ext_vector_type(4)));
typedef short s8v __attribute__((ext_vector_type(8)));
typedef short s4v __attribute__((ext_vector_type(4)));

#define NND 65536   // nodes
#define CHF 32768   // FFN/policy row-chunk (hb spans t0+arena = 128 MB)

#define VM2 asm volatile("s_waitcnt vmcnt(2)" ::: "memory")
#define VM0 asm volatile("s_waitcnt vmcnt(0)" ::: "memory")
#define BAR __builtin_amdgcn_s_barrier()
#define SCB __builtin_amdgcn_sched_barrier(0)

__device__ __forceinline__ float bs2f(short s) {
    union { unsigned u; float f; } x;
    x.u = ((unsigned)(u16)s) << 16;
    return x.f;
}
__device__ __forceinline__ u16 f2bu(float f) {
    union { float f; unsigned u; } x;
    x.f = f;
    unsigned r = x.u + 0x7FFFu + ((x.u >> 16) & 1u);
    return (u16)(r >> 16);
}
__device__ __forceinline__ void g2l16(const void* g, void* l) {
    __builtin_amdgcn_global_load_lds((const __attribute__((address_space(1))) void*)g,
                                     (__attribute__((address_space(3))) void*)l, 16, 0, 0);
}
// grouped XCD swizzle: all col-blocks (bn) of a row-tile (bm) land on one XCD
__device__ __forceinline__ void xcd_decode(int lognbn, int& bm, int& bn) {
    int flat = blockIdx.x;
    int cpx = gridDim.x >> 3;
    int virt = (flat & 7) * cpx + (flat >> 3);
    bm = virt >> lognbn;
    bn = virt & ((1 << lognbn) - 1);
}

// ---------------------------------------------------------------------------
// Per-layer wq/wk/wv conversion: fp32 (512x64) -> bf16 transposed (64x512).
// ---------------------------------------------------------------------------
__global__ void k_conv_qkv(const float* __restrict__ wq, const float* __restrict__ wk,
                           const float* __restrict__ wv, u16* __restrict__ wqT,
                           u16* __restrict__ wkT, u16* __restrict__ wvT, int l)
{
    int bz = blockIdx.y;
    const float* in; u16* out;
    if (bz < 40) {
        int h = bz / 5, r = bz % 5;
        in  = wk + (size_t)((l * 8 + h) * 5 + r) * 32768;
        out = wkT + (size_t)r * 262144 + h * 64 * 512;
    } else if (bz < 80) {
        int t = bz - 40; int h = t / 5, r = t % 5;
        in  = wv + (size_t)((l * 8 + h) * 5 + r) * 32768;
        out = wvT + (size_t)r * 262144 + h * 64 * 512;
    } else {
        int h = bz - 80;
        in  = wq + (size_t)(l * 8 + h) * 32768;
        out = wqT + h * 64 * 512;
    }
    int d0 = blockIdx.x * 32;
    __shared__ float s[32][65];
    int tid = threadIdx.x;
    int di = tid >> 3, k8 = (tid & 7) * 8;
    const float* ip = in + (long)(d0 + di) * 64 + k8;
    #pragma unroll
    for (int i = 0; i < 8; ++i) s[di][k8 + i] = ip[i];
    __syncthreads();
    int kk = tid >> 2, d8 = (tid & 3) * 8;
    s8v o;
    #pragma unroll
    for (int i = 0; i < 8; ++i) o[i] = (short)f2bu(s[d8 + i][kk]);
    *(s8v*)(out + (long)kk * 512 + d0 + d8) = o;
}

// Generic transpose: in (R x C fp32) -> out (C x R bf16). grid = (R/32)*(C/32).
__global__ void k_convT(const float* __restrict__ in, u16* __restrict__ out, int R, int C)
{
    int tiles_c = C >> 5;
    int tr = blockIdx.x / tiles_c, tc = blockIdx.x % tiles_c;
    int r0 = tr * 32, c0 = tc * 32;
    __shared__ float s[32][33];
    int tid = threadIdx.x;
    int ri = tid >> 3, c4 = (tid & 7) * 4;
    const float4 v = *(const float4*)(in + (long)(r0 + ri) * C + c0 + c4);
    s[ri][c4] = v.x; s[ri][c4 + 1] = v.y; s[ri][c4 + 2] = v.z; s[ri][c4 + 3] = v.w;
    __syncthreads();
    int ci = tid >> 3, r4 = (tid & 7) * 4;
    s4v o;
    #pragma unroll
    for (int i = 0; i < 4; ++i) o[i] = (short)f2bu(s[r4 + i][ci]);
    *(s4v*)(out + (long)(c0 + ci) * R + r0 + r4) = o;
}

// pol_w2 (1024x10 fp32) -> B-fragment-ordered bf16 (cols padded to 16):
// w2f[s*512 + l*8 + j] = w2[s*32 + (l>>4)*8 + j][l&15]  (0 for col>=10)
__global__ void k_conv_w2f(const float* __restrict__ w2, u16* __restrict__ w2f)
{
    int tid = threadIdx.x;
    for (int t = tid; t < 2048; t += 512) {
        int s = t >> 6, l = t & 63;
        int m = l & 15;
        int kbase = s * 32 + ((l >> 4) << 3);
        s8v o;
        #pragma unroll
        for (int j = 0; j < 8; ++j) {
            float v = (m < 10) ? w2[(long)(kbase + j) * 10 + m] : 0.f;
            o[j] = (short)f2bu(v);
        }
        *(s8v*)(w2f + (long)s * 512 + l * 8) = o;
    }
}

// ---------------------------------------------------------------------------
// Embed: xbf = bf16(x6 @ embed_w + embed_b). block=512 (one row per block)
// ---------------------------------------------------------------------------
__global__ void k_embed(const float* __restrict__ x6, const float* __restrict__ ew,
                        const float* __restrict__ eb, u16* __restrict__ xbf)
{
    int n = blockIdx.x, j = threadIdx.x;
    const float* r = x6 + (long)n * 6;
    float a = eb[j] + r[0] * ew[j] + r[1] * ew[512 + j] + r[2] * ew[1024 + j]
            + r[3] * ew[1536 + j] + r[4] * ew[2048 + j] + r[5] * ew[2560 + j];
    xbf[(long)n * 512 + j] = f2bu(a);
}

// ---------------------------------------------------------------------------
// bf16 MFMA GEMM: 128x128 tile, BK=32, 512 threads / 8 waves (4x2, wave tile
// 32x64), bank-conflict swizzle, 3-buffer LDS pipeline, counted vmcnt,
// setprio. BT = Ncols x K row-major. grouped-XCD 1-D grid.  (round-7 proven)
// ---------------------------------------------------------------------------
template<bool BIAS, bool RELU, bool ADDX>
__global__ __launch_bounds__(512, 4)
void k_gemm(const u16* __restrict__ A, const u16* __restrict__ BT,
            u16* __restrict__ C, const float* __restrict__ bias,
            const u16* __restrict__ resid, int K, int Ncols, int lognbn)
{
    __shared__ u16 sA[3][4096];
    __shared__ u16 sB[3][4096];
    const int tid = threadIdx.x;
    const int wave = tid >> 6, lane = tid & 63;
    int bm, bn;
    xcd_decode(lognbn, bm, bn);

    const int arow = tid >> 2;                              // 0..127
    const int acol8 = ((tid & 3) ^ ((tid >> 3) & 3)) * 8;   // source pre-swizzle
    const u16* pa = A + ((long)bm * 128 + arow) * K + acol8;
    const u16* pb = BT + ((long)bn * 128 + arow) * K + acol8;

    char* sAc = (char*)sA;
    char* sBc = (char*)sB;
    const int dst = tid * 16;

    f32x4 acc[2][4] = {};

    const int wm = wave >> 1, wn = wave & 1;                // 4x2 wave grid
    const int fr = lane & 15;
    const int g4 = lane >> 4;
    const int kbs = (g4 ^ ((fr >> 1) & 3)) * 16;            // swizzled read slot
    const char* ra = sAc + (wm * 32 + fr) * 64 + kbs;
    const char* rb = sBc + (wn * 64 + fr) * 64 + kbs;

    auto STAGE = [&](int buf) {
        g2l16(pa, sAc + buf * 8192 + dst);
        g2l16(pb, sBc + buf * 8192 + dst);
        pa += 32; pb += 32;
    };

    const int NT = K >> 5;
    STAGE(0); STAGE(1);
    VM2; BAR; SCB;

    int cur = 0, nx2 = 2;
    for (int t = 0; t < NT; ++t) {
        if (t + 2 < NT) STAGE(nx2);
        bf16x8 af[2], bfr[4];
        const char* rac = ra + cur * 8192;
        const char* rbc = rb + cur * 8192;
        #pragma unroll
        for (int mi = 0; mi < 2; ++mi) af[mi] = *(const bf16x8*)(rac + mi * 1024);
        #pragma unroll
        for (int ni = 0; ni < 4; ++ni) bfr[ni] = *(const bf16x8*)(rbc + ni * 1024);
        __builtin_amdgcn_s_setprio(1);
        #pragma unroll
        for (int mi = 0; mi < 2; ++mi)
            #pragma unroll
            for (int ni = 0; ni < 4; ++ni)
                acc[mi][ni] = __builtin_amdgcn_mfma_f32_16x16x32_bf16(af[mi], bfr[ni], acc[mi][ni], 0, 0, 0);
        __builtin_amdgcn_s_setprio(0);
        if (t + 2 < NT)      { VM2; }
        else if (t + 1 < NT) { VM0; }
        BAR; SCB;
        cur = (cur == 2) ? 0 : cur + 1;
        nx2 = (nx2 == 2) ? 0 : nx2 + 1;
    }

    const int crow0 = bm * 128 + wm * 32 + g4 * 4;
    const int ccol0 = bn * 128 + wn * 64 + fr;
    #pragma unroll
    for (int mi = 0; mi < 2; ++mi) {
        #pragma unroll
        for (int ni = 0; ni < 4; ++ni) {
            int col = ccol0 + ni * 16;
            float bv = BIAS ? bias[col] : 0.f;
            #pragma unroll
            for (int j = 0; j < 4; ++j) {
                int row = crow0 + mi * 16 + j;
                float v = acc[mi][ni][j] + bv;
                if (ADDX) v += bs2f(resid[(long)row * Ncols + col]);
                if (RELU) v = fmaxf(v, 0.f);
                C[(long)row * Ncols + col] = f2bu(v);
            }
        }
    }
}

// ---------------------------------------------------------------------------
// Fused attention pass A: phase 0 computes Q tile (registers, packed bf16),
// phases 1..5 compute K_r; S[h*5+r][n] = 0.125*dot64(Q,K) via elementwise
// frag product + 16-lane shfl reduce. 512 thr / 8 waves, pipelined K-loop.
// ---------------------------------------------------------------------------
__global__ __launch_bounds__(512, 4)
void k_attnKS(const u16* __restrict__ xbf, const u16* __restrict__ wqT,
              const u16* __restrict__ wkT, const int* __restrict__ adj,
              float* __restrict__ S)
{
    __shared__ u16 sA[3][4096];
    __shared__ u16 sB[3][4096];
    const int tid = threadIdx.x;
    const int wave = tid >> 6, lane = tid & 63;
    int bm, bn;
    xcd_decode(2, bm, bn);
    const int arow = tid >> 2;
    const int acol8 = ((tid & 3) ^ ((tid >> 3) & 3)) * 8;

    char* sAc = (char*)sA;
    char* sBc = (char*)sB;
    const int dst = tid * 16;

    const int wm = wave >> 1, wn = wave & 1;
    const int fr = lane & 15;
    const int g4 = lane >> 4;
    const int kbs = (g4 ^ ((fr >> 1) & 3)) * 16;
    const char* ra = sAc + (wm * 32 + fr) * 64 + kbs;
    const char* rb = sBc + (wn * 64 + fr) * 64 + kbs;

    const int h = bn * 2 + wn;
    const int rowbase = bm * 128 + wm * 32;

    unsigned qp[2][4][2];   // Q fragments, packed bf16 pairs

    for (int ph = 0; ph < 6; ++ph) {
        long r0 = (long)bm * 128 + arow;
        if (ph >= 2) r0 = adj[r0 * 4 + (ph - 2)];
        const u16* pa = xbf + r0 * 512 + acol8;
        const u16* bw = (ph == 0) ? wqT : wkT + (size_t)(ph - 1) * 262144;
        const u16* pb = bw + ((long)bn * 128 + arow) * 512 + acol8;

        auto STAGE = [&](int buf) {
            g2l16(pa, sAc + buf * 8192 + dst);
            g2l16(pb, sBc + buf * 8192 + dst);
            pa += 32; pb += 32;
        };

        STAGE(0); STAGE(1);
        VM2; BAR; SCB;

        f32x4 acc[2][4] = {};
        int cur = 0, nx2 = 2;
        for (int t = 0; t < 16; ++t) {
            if (t + 2 < 16) STAGE(nx2);
            bf16x8 af[2], bfr[4];
            const char* rac = ra + cur * 8192;
            const char* rbc = rb + cur * 8192;
            #pragma unroll
            for (int mi = 0; mi < 2; ++mi) af[mi] = *(const bf16x8*)(rac + mi * 1024);
            #pragma unroll
            for (int ni = 0; ni < 4; ++ni) bfr[ni] = *(const bf16x8*)(rbc + ni * 1024);
            __builtin_amdgcn_s_setprio(1);
            #pragma unroll
            for (int mi = 0; mi < 2; ++mi)
                #pragma unroll
                for (int ni = 0; ni < 4; ++ni)
                    acc[mi][ni] = __builtin_amdgcn_mfma_f32_16x16x32_bf16(af[mi], bfr[ni], acc[mi][ni], 0, 0, 0);
            __builtin_amdgcn_s_setprio(0);
            if (t + 2 < 16)      { VM2; }
            else if (t + 1 < 16) { VM0; }
            BAR; SCB;
            cur = (cur == 2) ? 0 : cur + 1;
            nx2 = (nx2 == 2) ? 0 : nx2 + 1;
        }

        if (ph == 0) {
            #pragma unroll
            for (int mi = 0; mi < 2; ++mi)
                #pragma unroll
                for (int ni = 0; ni < 4; ++ni)
                    #pragma unroll
                    for (int jj = 0; jj < 2; ++jj)
                        qp[mi][ni][jj] = (unsigned)f2bu(acc[mi][ni][2 * jj])
                                       | ((unsigned)f2bu(acc[mi][ni][2 * jj + 1]) << 16);
        } else {
            int sc = h * 5 + (ph - 1);
            #pragma unroll
            for (int mi = 0; mi < 2; ++mi) {
                float pj[4];
                #pragma unroll
                for (int j = 0; j < 4; ++j) {
                    float s = 0.f;
                    #pragma unroll
                    for (int ni = 0; ni < 4; ++ni) {
                        unsigned w = qp[mi][ni][j >> 1];
                        u16 qh = (j & 1) ? (u16)(w >> 16) : (u16)(w & 0xffff);
                        s += acc[mi][ni][j] * bs2f((short)qh);
                    }
                    #pragma unroll
                    for (int m = 1; m < 16; m <<= 1) s += __shfl_xor(s, m);
                    pj[j] = s * 0.125f;
                }
                if (fr == 0) {
                    float4 o; o.x = pj[0]; o.y = pj[1]; o.z = pj[2]; o.w = pj[3];
                    *(float4*)&S[(size_t)sc * NND + rowbase + mi * 16 + g4 * 4] = o;
                }
            }
        }
    }
}

// Per-(h,r) column logsumexp over the node axis. S layout [40][N].
__global__ void k_colstats(const float* __restrict__ S, float* __restrict__ stats)
{
    int col = blockIdx.x;     // 0..39
    int tid = threadIdx.x;
    const float* Sc = S + (size_t)col * NND;
    float m = -1e30f, s = 0.f;
    for (int n = tid; n < NND; n += 256) {
        float v = Sc[n];
        if (v > m) { s = s * __expf(m - v) + 1.f; m = v; }
        else s += __expf(v - m);
    }
    __shared__ float smx[256], ssm[256];
    smx[tid] = m; ssm[tid] = s;
    __syncthreads();
    for (int off = 128; off; off >>= 1) {
        if (tid < off) {
            float m2 = smx[tid + off], s2 = ssm[tid + off];
            float M = fmaxf(smx[tid], m2);
            ssm[tid] = ssm[tid] * __expf(smx[tid] - M) + s2 * __expf(m2 - M);
            smx[tid] = M;
        }
        __syncthreads();
    }
    if (tid == 0) stats[col] = smx[0] + __logf(ssm[0]);   // logsumexp L
}

// ---------------------------------------------------------------------------
// Fused attention pass B: 5 V_r phases Horner-accumulated in the MFMA
// accumulator. Epilogue: t0 = xbf + Z (bf16). 512 thr / 8 waves, pipelined.
// ---------------------------------------------------------------------------
__global__ __launch_bounds__(512, 4)
void k_attnVZ(const u16* __restrict__ xbf, const u16* __restrict__ wvT,
              const int* __restrict__ adj, const float* __restrict__ S,
              const float* __restrict__ stats, u16* __restrict__ t0)
{
    __shared__ u16 sA[3][4096];
    __shared__ u16 sB[3][4096];
    const int tid = threadIdx.x;
    const int wave = tid >> 6, lane = tid & 63;
    int bm, bn;
    xcd_decode(2, bm, bn);
    const int arow = tid >> 2;
    const int acol8 = ((tid & 3) ^ ((tid >> 3) & 3)) * 8;

    char* sAc = (char*)sA;
    char* sBc = (char*)sB;
    const int dst = tid * 16;

    const int wm = wave >> 1, wn = wave & 1;
    const int fr = lane & 15;
    const int g4 = lane >> 4;
    const int kbs = (g4 ^ ((fr >> 1) & 3)) * 16;
    const char* ra = sAc + (wm * 32 + fr) * 64 + kbs;
    const char* rb = sBc + (wn * 64 + fr) * 64 + kbs;

    const int h = bn * 2 + wn;
    const int rowbase = bm * 128 + wm * 32;

    f32x4 acc[2][4] = {};

    for (int ph = 0; ph < 5; ++ph) {
        long r0 = (long)bm * 128 + arow;
        if (ph >= 1) r0 = adj[r0 * 4 + (ph - 1)];
        const u16* pa = xbf + r0 * 512 + acol8;
        const u16* pb = wvT + (size_t)ph * 262144 + ((long)bn * 128 + arow) * 512 + acol8;

        auto STAGE = [&](int buf) {
            g2l16(pa, sAc + buf * 8192 + dst);
            g2l16(pb, sBc + buf * 8192 + dst);
            pa += 32; pb += 32;
        };

        STAGE(0); STAGE(1);
        VM2; BAR; SCB;

        int cur = 0, nx2 = 2;
        for (int t = 0; t < 16; ++t) {
            if (t + 2 < 16) STAGE(nx2);
            bf16x8 af[2], bfr[4];
            const char* rac = ra + cur * 8192;
            const char* rbc = rb + cur * 8192;
            #pragma unroll
            for (int mi = 0; mi < 2; ++mi) af[mi] = *(const bf16x8*)(rac + mi * 1024);
            #pragma unroll
            for (int ni = 0; ni < 4; ++ni) bfr[ni] = *(const bf16x8*)(rbc + ni * 1024);
            __builtin_amdgcn_s_setprio(1);
            #pragma unroll
            for (int mi = 0; mi < 2; ++mi)
                #pragma unroll
                for (int ni = 0; ni < 4; ++ni)
                    acc[mi][ni] = __builtin_amdgcn_mfma_f32_16x16x32_bf16(af[mi], bfr[ni], acc[mi][ni], 0, 0, 0);
            __builtin_amdgcn_s_setprio(0);
            if (t + 2 < 16)      { VM2; }
            else if (t + 1 < 16) { VM0; }
            BAR; SCB;
            cur = (cur == 2) ? 0 : cur + 1;
            nx2 = (nx2 == 2) ? 0 : nx2 + 1;
        }

        int sc = h * 5 + ph;
        if (ph < 4) {
            // Horner: acc *= a_ph / a_{ph+1}
            float Lc = stats[sc], Ln = stats[sc + 1];
            #pragma unroll
            for (int mi = 0; mi < 2; ++mi) {
                int rb4 = rowbase + mi * 16 + g4 * 4;
                float4 c4 = *(const float4*)&S[(size_t)sc * NND + rb4];
                float4 n4 = *(const float4*)&S[(size_t)(sc + 1) * NND + rb4];
                float rt[4];
                rt[0] = __expf((c4.x - Lc) - (n4.x - Ln));
                rt[1] = __expf((c4.y - Lc) - (n4.y - Ln));
                rt[2] = __expf((c4.z - Lc) - (n4.z - Ln));
                rt[3] = __expf((c4.w - Lc) - (n4.w - Ln));
                #pragma unroll
                for (int ni = 0; ni < 4; ++ni)
                    #pragma unroll
                    for (int j = 0; j < 4; ++j)
                        acc[mi][ni][j] *= rt[j];
            }
        } else {
            // final scale by a_4 and write t0 = xbf + Z
            float Lc = stats[sc];
            #pragma unroll
            for (int mi = 0; mi < 2; ++mi) {
                int rb4 = rowbase + mi * 16 + g4 * 4;
                float4 c4 = *(const float4*)&S[(size_t)sc * NND + rb4];
                float a[4];
                a[0] = __expf(c4.x - Lc);
                a[1] = __expf(c4.y - Lc);
                a[2] = __expf(c4.z - Lc);
                a[3] = __expf(c4.w - Lc);
                #pragma unroll
                for (int ni = 0; ni < 4; ++ni) {
                    int col = bn * 128 + wn * 64 + ni * 16 + fr;
                    #pragma unroll
                    for (int j = 0; j < 4; ++j) {
                        long row = rb4 + j;
                        float v = acc[mi][ni][j] * a[j] + bs2f(xbf[row * 512 + col]);
                        t0[row * 512 + col] = f2bu(v);
                    }
                }
            }
        }
    }
}

// x = bf16(LayerNorm(t) * g + b). block=128 (1 row). Safe with t == x.
__global__ void k_ln(const u16* __restrict__ t, u16* __restrict__ x,
                     const float* __restrict__ g, const float* __restrict__ b)
{
    int n = blockIdx.x, tid = threadIdx.x;
    long base = (long)n * 512 + tid * 4;
    s4v tv = *(const s4v*)(t + base);
    float v0 = bs2f(tv[0]), v1 = bs2f(tv[1]), v2 = bs2f(tv[2]), v3 = bs2f(tv[3]);
    float s1 = v0 + v1 + v2 + v3;
    float s2 = v0 * v0 + v1 * v1 + v2 * v2 + v3 * v3;
    #pragma unroll
    for (int off = 32; off; off >>= 1) {
        s1 += __shfl_down(s1, off);
        s2 += __shfl_down(s2, off);
    }
    __shared__ float a1[2], a2[2];
    int w = tid >> 6, lane = tid & 63;
    if (lane == 0) { a1[w] = s1; a2[w] = s2; }
    __syncthreads();
    float S1 = a1[0] + a1[1], S2 = a2[0] + a2[1];
    float mu = S1 * (1.f / 512.f);
    float var = S2 * (1.f / 512.f) - mu * mu;
    float rs = rsqrtf(var + 1e-5f);
    int c = tid * 4;
    s4v ob;
    ob[0] = (short)f2bu((v0 - mu) * rs * g[c] + b[c]);
    ob[1] = (short)f2bu((v1 - mu) * rs * g[c + 1] + b[c + 1]);
    ob[2] = (short)f2bu((v2 - mu) * rs * g[c + 2] + b[c + 2]);
    ob[3] = (short)f2bu((v3 - mu) * rs * g[c + 3] + b[c + 3]);
    *(s4v*)(x + base) = ob;
}

// Policy second GEMM via MFMA, no LDS: out[n,m<10] = p1[n,:1024]@w2 + b2.
// w2f is B-fragment-ordered bf16 (32 k-steps x 512). 8 waves x 16 rows/block.
__global__ __launch_bounds__(512)
void k_pol2m(const u16* __restrict__ p1, const u16* __restrict__ w2f,
             const float* __restrict__ b2, float* __restrict__ out)
{
    const int wave = threadIdx.x >> 6, lane = threadIdx.x & 63;
    const long n0 = ((long)blockIdx.x * 8 + wave) * 16;
    const int row = lane & 15;
    const int ko = (lane >> 4) * 8;
    const u16* pa = p1 + (n0 + row) * 1024 + ko;
    f32x4 acc = {};
    #pragma unroll 4
    for (int s = 0; s < 32; ++s) {
        bf16x8 a = *(const bf16x8*)(pa + s * 32);
        bf16x8 b = *(const bf16x8*)(w2f + s * 512 + lane * 8);
        acc = __builtin_amdgcn_mfma_f32_16x16x32_bf16(a, b, acc, 0, 0, 0);
    }
    const int col = lane & 15;
    if (col < 10) {
        float bv = b2[col];
        #pragma unroll
        for (int j = 0; j < 4; ++j)
            out[(n0 + (lane >> 4) * 4 + j) * 10 + col] = acc[j] + bv;
    }
}

__global__ void k_offsets(const int* __restrict__ bs, int* __restrict__ offs)
{
    if (threadIdx.x == 0) {
        int acc = 0;
        for (int i = 0; i < 128; ++i) { offs[i] = acc; acc += bs[i]; }
        offs[128] = acc;
    }
}

// Segment mean-pool over bf16 residual. block=128, 4 cols/thread.
__global__ void k_pool(const u16* __restrict__ x, const int* __restrict__ offs,
                       const int* __restrict__ bs, float* __restrict__ pooled)
{
    int g = blockIdx.x, tid = threadIdx.x;
    int c = tid * 4;
    int r0 = offs[g], r1 = offs[g + 1];
    float a0 = 0.f, a1 = 0.f, a2 = 0.f, a3 = 0.f;
    for (int rr = r0; rr < r1; ++rr) {
        s4v v = *(const s4v*)(x + (long)rr * 512 + c);
        a0 += bs2f(v[0]); a1 += bs2f(v[1]); a2 += bs2f(v[2]); a3 += bs2f(v[3]);
    }
    float d = fmaxf((float)bs[g], 1e-9f);
    pooled[g * 512 + c] = a0 / d;
    pooled[g * 512 + c + 1] = a1 / d;
    pooled[g * 512 + c + 2] = a2 / d;
    pooled[g * 512 + c + 3] = a3 / d;
}

__global__ void k_val1(const float* __restrict__ pooled, const float* __restrict__ w1,
                       const float* __restrict__ b1, float* __restrict__ v1)
{
    int g = blockIdx.x;
    int j = blockIdx.y * 256 + threadIdx.x;
    __shared__ float sp[512];
    for (int i = threadIdx.x; i < 512; i += 256) sp[i] = pooled[g * 512 + i];
    __syncthreads();
    float a = b1[j];
    for (int d = 0; d < 512; ++d) a += sp[d] * w1[(long)d * 1024 + j];
    v1[g * 1024 + j] = fmaxf(a, 0.f);
}

__global__ void k_val2(const float* __restrict__ v1, const float* __restrict__ w2,
                       const float* __restrict__ b2, float* __restrict__ out)
{
    int g = blockIdx.x, lane = threadIdx.x;
    float a = 0.f;
    for (int k = lane; k < 1024; k += 64) a += v1[g * 1024 + k] * w2[k];
    #pragma unroll
    for (int off = 32; off; off >>= 1) a += __shfl_down(a, off);
    if (lane == 0) out[(long)NND * 10 + g] = tanhf(a + b2[0]);
}

// ---------------------------------------------------------------------------
extern "C" void kernel_launch(void* const* d_in, const int* in_sizes, int n_in,
                              void* d_out, int out_size, void* d_ws, size_t ws_size,
                              hipStream_t stream)
{
    (void)in_sizes; (void)n_in; (void)out_size; (void)ws_size;
    const float* x6        = (const float*)d_in[0];
    const int*   adjacency = (const int*)d_in[1];
    const int*   batch_sz  = (const int*)d_in[2];
    const float* embed_w   = (const float*)d_in[3];
    const float* embed_b   = (const float*)d_in[4];
    const float* wq        = (const float*)d_in[5];
    const float* wk        = (const float*)d_in[6];
    const float* wv        = (const float*)d_in[7];
    const float* ffn_w1    = (const float*)d_in[8];
    const float* ffn_b1    = (const float*)d_in[9];
    const float* ffn_w2    = (const float*)d_in[10];
    const float* ffn_b2    = (const float*)d_in[11];
    const float* ln1_g     = (const float*)d_in[12];
    const float* ln1_b     = (const float*)d_in[13];
    const float* ln2_g     = (const float*)d_in[14];
    const float* ln2_b     = (const float*)d_in[15];
    const float* pol_w1    = (const float*)d_in[16];
    const float* pol_b1    = (const float*)d_in[17];
    const float* pol_w2    = (const float*)d_in[18];
    const float* pol_b2    = (const float*)d_in[19];
    const float* val_w1    = (const float*)d_in[20];
    const float* val_b1    = (const float*)d_in[21];
    const float* val_w2    = (const float*)d_in[22];
    const float* val_b2    = (const float*)d_in[23];
    float* out = (float*)d_out;

    char* ws = (char*)d_ws;
    size_t off = 0;
    auto alloc = [&](size_t bytes) {
        char* p = ws + off;
        off = (off + bytes + 255) & ~(size_t)255;
        return p;
    };
    // ~212 MB total (round-2-proven budget)
    u16*   xbf  = (u16*)  alloc((size_t)NND * 512 * 2);      // 64 MB residual
    u16*   t0   = (u16*)  alloc((size_t)NND * 512 * 2);      // 64 MB x+Z (dead during FFN)
    char*  arena=         alloc((size_t)NND * 512 * 2);      // 64 MB; t0+arena = 128 MB hb span
    float* S    = (float*)alloc((size_t)40 * NND * 4);       // 10.5 MB scores [40][N]
    float* stats= (float*)alloc(4096);
    float* pooled=(float*)alloc(128 * 512 * 4);
    float* v1   = (float*)alloc(128 * 1024 * 4);
    int*   offs = (int*)  alloc(1024);
    u16*   wqTl = (u16*)  alloc((size_t)262144 * 2);         // per-layer slabs
    u16*   wkTl = (u16*)  alloc((size_t)5 * 262144 * 2);
    u16*   wvTl = (u16*)  alloc((size_t)5 * 262144 * 2);
    u16*   w1Tl = (u16*)  alloc((size_t)2048 * 512 * 2);
    u16*   w2Tl = (u16*)  alloc((size_t)512 * 2048 * 2);
    u16*   pw1T = (u16*)  alloc((size_t)1024 * 512 * 2);
    u16*   w2f  = (u16*)  alloc((size_t)16384 * 2);          // pol_w2 B-frag order

    u16* hb  = t0;              // CHF x 2048 bf16 = 128 MB, spans t0+arena
    u16* p1c = (u16*)arena;     // CHF x 1024 bf16 = 64 MB

    k_convT<<<512, 256, 0, stream>>>(pol_w1, pw1T, 512, 1024);
    k_conv_w2f<<<1, 512, 0, stream>>>(pol_w2, w2f);
    k_offsets<<<1, 128, 0, stream>>>(batch_sz, offs);
    k_embed<<<NND, 512, 0, stream>>>(x6, embed_w, embed_b, xbf);

    for (int l = 0; l < 4; ++l) {
        k_conv_qkv<<<dim3(16, 88), 256, 0, stream>>>(wq, wk, wv, wqTl, wkTl, wvTl, l);
        k_convT<<<1024, 256, 0, stream>>>(ffn_w1 + (size_t)l * 512 * 2048, w1Tl, 512, 2048);
        k_convT<<<1024, 256, 0, stream>>>(ffn_w2 + (size_t)l * 2048 * 512, w2Tl, 2048, 512);

        k_attnKS<<<2048, 512, 0, stream>>>(xbf, wqTl, wkTl, adjacency, S);
        k_colstats<<<40, 256, 0, stream>>>(S, stats);
        k_attnVZ<<<2048, 512, 0, stream>>>(xbf, wvTl, adjacency, S, stats, t0);
        k_ln<<<NND, 128, 0, stream>>>(t0, xbf, ln1_g + l * 512, ln1_b + l * 512);
        // FFN: hb spans t0+arena (t0 dead here); w2 writes xbf in place.
        for (int c = 0; c < NND / CHF; ++c) {
            size_t row0 = (size_t)c * CHF;
            k_gemm<true,true,false><<<4096, 512, 0, stream>>>(
                xbf + row0 * 512, w1Tl, hb, ffn_b1 + l * 2048, nullptr, 512, 2048, 4);
            k_gemm<true,false,true><<<1024, 512, 0, stream>>>(
                hb, w2Tl, xbf + row0 * 512, ffn_b2 + l * 512, xbf + row0 * 512, 2048, 512, 2);
        }
        k_ln<<<NND, 128, 0, stream>>>(xbf, xbf, ln2_g + l * 512, ln2_b + l * 512);
    }

    // Policy head per row-chunk
    for (int c = 0; c < NND / CHF; ++c) {
        size_t row0 = (size_t)c * CHF;
        k_gemm<true,true,false><<<2048, 512, 0, stream>>>(
            xbf + row0 * 512, pw1T, p1c, pol_b1, nullptr, 512, 1024, 3);
        k_pol2m<<<CHF / 128, 512, 0, stream>>>(p1c, w2f, pol_b2, out + row0 * 10);
    }
    // Value head
    k_pool<<<128, 128, 0, stream>>>(xbf, offs, batch_sz, pooled);
    k_val1<<<dim3(128, 4), 256, 0, stream>>>(pooled, val_w1, val_b1, v1);
    k_val2<<<128, 64, 0, stream>>>(v1, val_w2, val_b2, out);
}